// Round 1
// baseline (28018.936 us; speedup 1.0000x reference)
//
#include <hip/hip_runtime.h>
#include <math.h>

// Sizes (fixed by the problem)
#define BATCH   64
#define SEQ     512
#define NIN     512
#define NHID    1024
#define NOUT    512

// ---------------- Tiled fp32 GEMM with bias: C[M,N] = A[M,K] @ B[K,N] + bias[N]
// BM=BN=64, BK=16, 256 threads, each thread computes a 4x4 microtile.
#define BM 64
#define BN 64
#define BK 16

__global__ __launch_bounds__(256) void gemm_bias(
    const float* __restrict__ A, const float* __restrict__ B,
    const float* __restrict__ bias, float* __restrict__ C,
    int M, int N, int K) {
  // +4 pad keeps 16B alignment of rows (stride 68 floats = 272B, 16B-aligned)
  __shared__ float As[BK][BM + 4];  // transposed A tile: As[k][m]
  __shared__ float Bs[BK][BN + 4];  // Bs[k][n]

  const int tid = threadIdx.x;
  const int bx = blockIdx.x;  // N tile
  const int by = blockIdx.y;  // M tile

  const int tm = (tid / 16) * 4;   // 0..60, row of microtile
  const int tn = (tid % 16) * 4;   // 0..60, col of microtile

  // A-tile load mapping: 64 rows x 16 k; each thread loads float4 of k
  const int ar = tid / 4;            // 0..63
  const int ac = (tid % 4) * 4;      // 0,4,8,12
  // B-tile load mapping: 16 k x 64 n; each thread loads float4 of n
  const int br = tid / 16;           // 0..15
  const int bc = (tid % 16) * 4;     // 0..60

  float acc[4][4] = {};

  for (int k0 = 0; k0 < K; k0 += BK) {
    float4 av = *(const float4*)&A[(size_t)(by * BM + ar) * K + k0 + ac];
    As[ac + 0][ar] = av.x;
    As[ac + 1][ar] = av.y;
    As[ac + 2][ar] = av.z;
    As[ac + 3][ar] = av.w;
    float4 bv = *(const float4*)&B[(size_t)(k0 + br) * N + bx * BN + bc];
    *(float4*)&Bs[br][bc] = bv;
    __syncthreads();

#pragma unroll
    for (int k = 0; k < BK; ++k) {
      float4 a4 = *(const float4*)&As[k][tm];
      float4 b4 = *(const float4*)&Bs[k][tn];
      float ae[4] = {a4.x, a4.y, a4.z, a4.w};
      float be[4] = {b4.x, b4.y, b4.z, b4.w};
#pragma unroll
      for (int i = 0; i < 4; ++i)
#pragma unroll
        for (int j = 0; j < 4; ++j)
          acc[i][j] += ae[i] * be[j];
    }
    __syncthreads();
  }

  const float4 bb = *(const float4*)&bias[bx * BN + tn];
#pragma unroll
  for (int i = 0; i < 4; ++i) {
    float4 o;
    o.x = acc[i][0] + bb.x;
    o.y = acc[i][1] + bb.y;
    o.z = acc[i][2] + bb.z;
    o.w = acc[i][3] + bb.w;
    *(float4*)&C[(size_t)(by * BM + tm + i) * N + bx * BN + tn] = o;
  }
}

// ---------------- Recurrent scan: one block per batch element.
// h[1024] lives in LDS. xi buffer [B,S,H] is overwritten in place with h_t.
__global__ __launch_bounds__(256) void rnn_scan(
    const float* __restrict__ Wh, float* __restrict__ xi) {
  __shared__ float h[NHID];
  const int b = blockIdx.x;
  const int tid = threadIdx.x;  // 0..255; each thread owns 4 consecutive j

  for (int j = tid; j < NHID; j += 256) h[j] = 0.f;
  __syncthreads();

  const float4* __restrict__ Wh4 = (const float4*)Wh;  // [NHID][NHID/4]
  float4* xrow = (float4*)(xi + (size_t)b * SEQ * NHID);

  for (int t = 0; t < SEQ; ++t) {
    float acc0 = 0.f, acc1 = 0.f, acc2 = 0.f, acc3 = 0.f;
#pragma unroll 4
    for (int k = 0; k < NHID; ++k) {
      float hk = h[k];
      float4 w = Wh4[(size_t)k * (NHID / 4) + tid];
      acc0 += hk * w.x;
      acc1 += hk * w.y;
      acc2 += hk * w.z;
      acc3 += hk * w.w;
    }
    float4 xv = xrow[t * (NHID / 4) + tid];
    float4 hn;
    hn.x = fmaxf(tanhf(xv.x + acc0), 0.f);
    hn.y = fmaxf(tanhf(xv.y + acc1), 0.f);
    hn.z = fmaxf(tanhf(xv.z + acc2), 0.f);
    hn.w = fmaxf(tanhf(xv.w + acc3), 0.f);
    __syncthreads();  // all reads of h done before overwrite
    ((float4*)h)[tid] = hn;
    xrow[t * (NHID / 4) + tid] = hn;  // stash h_t for the output GEMM
    __syncthreads();
  }
}

extern "C" void kernel_launch(void* const* d_in, const int* in_sizes, int n_in,
                              void* d_out, int out_size, void* d_ws, size_t ws_size,
                              hipStream_t stream) {
  const float* x  = (const float*)d_in[0];  // [64,512,512]
  const float* Wi = (const float*)d_in[1];  // [512,1024]
  const float* bi = (const float*)d_in[2];  // [1024]
  const float* Wh = (const float*)d_in[3];  // [1024,1024]
  const float* Wo = (const float*)d_in[4];  // [1024,512]
  const float* bo = (const float*)d_in[5];  // [512]
  float* out = (float*)d_out;               // [64,512,512]
  float* xi  = (float*)d_ws;                // [64,512,1024] = 128 MB scratch

  const int M = BATCH * SEQ;  // 32768

  dim3 blk(256);
  // xi = x @ Wi + bi
  gemm_bias<<<dim3(NHID / BN, M / BM), blk, 0, stream>>>(x, Wi, bi, xi, M, NHID, NIN);
  // sequential scan, overwrites xi with h_t
  rnn_scan<<<dim3(BATCH), blk, 0, stream>>>(Wh, xi);
  // y = h @ Wo + bo
  gemm_bias<<<dim3(NOUT / BN, M / BM), blk, 0, stream>>>(xi, Wo, bo, out, M, NOUT, NHID);
}